// Round 1
// baseline (199.428 us; speedup 1.0000x reference)
//
#include <hip/hip_runtime.h>

// RegLoss: l1(masked preds, targets) + 0.1 * mse(masked edge directions)
// preds, targets: [128, 1024, 151] fp32. Output: 1 fp32 scalar.
//
// Identities used:
//   targets_m = targets * (targets != 0)  ==  targets          (identity)
//   (m*pd - m*td)^2 = m*(pd - td)^2       (m in {0,1})
// directs channel layout after transpose(0,1,3,2): channel = comp*47 + edge,
// and mask applied to it is mask channel comp*47+edge of the SAME row.

#define N_ROWS   (128 * 1024)
#define ROW      151
#define N_EDGES  47
#define GRID     1024
#define BLOCK    256
// fixed-point scale for u64 atomic accumulation
#define FP_SCALE 1048576.0   // 2^20

__constant__ int c_par[N_EDGES] = {
    0, 1, 2, 3, 1, 5, 6, 8, 8, 8, 8, 8, 9, 10, 11, 13, 14, 15, 17, 18, 19,
    21, 22, 23, 25, 26, 27, 29, 29, 29, 29, 29, 30, 31, 32, 34, 35, 36, 38,
    39, 40, 42, 43, 44, 46, 47, 48};
__constant__ int c_chd[N_EDGES] = {
    1, 2, 3, 29, 5, 6, 8, 9, 13, 17, 21, 25, 10, 11, 12, 14, 15, 16, 18, 19,
    20, 22, 23, 24, 26, 27, 28, 30, 34, 38, 42, 46, 31, 32, 33, 35, 36, 37,
    39, 40, 41, 43, 44, 45, 47, 48, 49};

__global__ __launch_bounds__(BLOCK) void reg_loss_main(
        const float* __restrict__ preds, const float* __restrict__ targets,
        unsigned long long* __restrict__ ws) {
    // per-wave LDS staging: masked preds + raw targets for one row
    __shared__ float pmS[4][152];
    __shared__ float tmS[4][152];
    __shared__ float redL[4], redV[4];

    const int lane = threadIdx.x & 63;
    const int wave = threadIdx.x >> 6;

    // per-lane edge assignment (fixed across loop)
    int pi = 0, ci = 0;
    if (lane < N_EDGES) {
        pi = c_par[lane] * 3;
        ci = c_chd[lane] * 3;
    }

    float l1 = 0.f;
    float vel = 0.f;

    const int waveGlobal = blockIdx.x * 4 + wave;
    const int waveStride = GRID * 4;   // 4096; N_ROWS / 4096 = 32 exactly

    for (int row = waveGlobal; row < N_ROWS; row += waveStride) {
        const long long base = (long long)row * ROW;
        // --- stage row into LDS (coalesced dword loads) + l1 partial ---
#pragma unroll
        for (int k = 0; k < 3; ++k) {
            int idx = lane + k * 64;
            if (idx < ROW) {
                float t = targets[base + idx];
                float p = preds[base + idx];
                float pm = (t != 0.f) ? p : 0.f;   // preds * mask
                l1 += fabsf(pm - t);               // |preds_m - targets_m|
                pmS[wave][idx] = pm;
                tmS[wave][idx] = t;
            }
        }
        __syncthreads();
        // --- edges: lanes 0..46 ---
        if (lane < N_EDGES) {
            float pdx = pmS[wave][pi]     - pmS[wave][ci];
            float pdy = pmS[wave][pi + 1] - pmS[wave][ci + 1];
            float pdz = pmS[wave][pi + 2] - pmS[wave][ci + 2];
            float tdx = tmS[wave][pi]     - tmS[wave][ci];
            float tdy = tmS[wave][pi + 1] - tmS[wave][ci + 1];
            float tdz = tmS[wave][pi + 2] - tmS[wave][ci + 2];
            const float eps = 1.17549435e-38f;  // finfo(float32).tiny
            float plen = sqrtf(pdx * pdx + pdy * pdy + pdz * pdz);
            float tlen = sqrtf(tdx * tdx + tdy * tdy + tdz * tdz);
            float pinv = 1.f / (plen + eps);
            float tinv = 1.f / (tlen + eps);
            float dx = pdx * pinv - tdx * tinv;
            float dy = pdy * pinv - tdy * tinv;
            float dz = pdz * pinv - tdz * tinv;
            // mask channels: comp*47 + edge
            float m0 = (tmS[wave][lane]          != 0.f) ? 1.f : 0.f;
            float m1 = (tmS[wave][47 + lane]     != 0.f) ? 1.f : 0.f;
            float m2 = (tmS[wave][94 + lane]     != 0.f) ? 1.f : 0.f;
            vel += m0 * dx * dx + m1 * dy * dy + m2 * dz * dz;
        }
        __syncthreads();   // protect LDS before next row overwrites
    }

    // --- wave reduce (width 64) ---
#pragma unroll
    for (int off = 32; off > 0; off >>= 1) {
        l1  += __shfl_down(l1, off);
        vel += __shfl_down(vel, off);
    }
    if (lane == 0) { redL[wave] = l1; redV[wave] = vel; }
    __syncthreads();
    if (threadIdx.x == 0) {
        float L = redL[0] + redL[1] + redL[2] + redL[3];
        float V = redV[0] + redV[1] + redV[2] + redV[3];
        unsigned long long uL = (unsigned long long)((double)L * FP_SCALE + 0.5);
        unsigned long long uV = (unsigned long long)((double)V * FP_SCALE + 0.5);
        atomicAdd(&ws[0], uL);
        atomicAdd(&ws[1], uV);
    }
}

__global__ void reg_loss_finalize(const unsigned long long* __restrict__ ws,
                                  float* __restrict__ out) {
    if (threadIdx.x == 0 && blockIdx.x == 0) {
        double L = (double)ws[0] * (1.0 / FP_SCALE);
        double V = (double)ws[1] * (1.0 / FP_SCALE);
        double res = L / ((double)N_ROWS * 151.0)
                   + 0.1 * (V / ((double)N_ROWS * 141.0));
        out[0] = (float)res;
    }
}

extern "C" void kernel_launch(void* const* d_in, const int* in_sizes, int n_in,
                              void* d_out, int out_size, void* d_ws, size_t ws_size,
                              hipStream_t stream) {
    const float* preds   = (const float*)d_in[0];
    const float* targets = (const float*)d_in[1];
    unsigned long long* ws = (unsigned long long*)d_ws;
    float* out = (float*)d_out;

    hipMemsetAsync(d_ws, 0, 2 * sizeof(unsigned long long), stream);
    reg_loss_main<<<GRID, BLOCK, 0, stream>>>(preds, targets, ws);
    reg_loss_finalize<<<1, 64, 0, stream>>>(ws, out);
}

// Round 2
// 189.191 us; speedup vs baseline: 1.0541x; 1.0541x over previous
//
#include <hip/hip_runtime.h>

// RegLoss: l1(masked preds, targets) + 0.1 * mse(masked edge directions)
// preds, targets: [128, 1024, 151] fp32. Output: 1 fp32 scalar.
//
// Identities:
//   targets * (targets != 0) == targets       (masking targets is identity)
//   (m*pd - m*td)^2 == m*(pd - td)^2          (m in {0,1})
// directs channel c = comp*47 + edge; its mask is mask[comp*47+edge] of the
// same row.
//
// Structure: 2048 blocks x 256 threads. Each block does 4 tiles of 16 rows.
// Phase 1: coalesced float4 tile load (tile = 16*151 dwords, %4==0 so every
// tile is 16B aligned), compute l1 + masked preds, stage into LDS.
// Phase 2: 752 edge tasks (16 rows x 47 edges) over all 256 threads.
// Per-block fp32 partials -> d_ws (no zero-init needed); 1-block finalize.

#define N_ROWS   (128 * 1024)
#define ROW      151
#define N_EDGES  47
#define GRID     2048
#define BLOCK    256
#define TILE_ROWS 16
#define TILES_PER_BLOCK 4              // GRID*4*16 = 131072 = N_ROWS exactly
#define TILE_DWORDS (TILE_ROWS * ROW)  // 2416 (divisible by 4)
#define TILE_F4 (TILE_DWORDS / 4)      // 604
#define N_TASKS (TILE_ROWS * N_EDGES)  // 752

// packed: low16 = parent*3, high16 = child*3
__constant__ unsigned int c_edge[N_EDGES] = {
    (0*3)|(1*3<<16),  (1*3)|(2*3<<16),  (2*3)|(3*3<<16),  (3*3)|(29*3<<16),
    (1*3)|(5*3<<16),  (5*3)|(6*3<<16),  (6*3)|(8*3<<16),  (8*3)|(9*3<<16),
    (8*3)|(13*3<<16), (8*3)|(17*3<<16), (8*3)|(21*3<<16), (8*3)|(25*3<<16),
    (9*3)|(10*3<<16), (10*3)|(11*3<<16),(11*3)|(12*3<<16),(13*3)|(14*3<<16),
    (14*3)|(15*3<<16),(15*3)|(16*3<<16),(17*3)|(18*3<<16),(18*3)|(19*3<<16),
    (19*3)|(20*3<<16),(21*3)|(22*3<<16),(22*3)|(23*3<<16),(23*3)|(24*3<<16),
    (25*3)|(26*3<<16),(26*3)|(27*3<<16),(27*3)|(28*3<<16),(29*3)|(30*3<<16),
    (29*3)|(34*3<<16),(29*3)|(38*3<<16),(29*3)|(42*3<<16),(29*3)|(46*3<<16),
    (30*3)|(31*3<<16),(31*3)|(32*3<<16),(32*3)|(33*3<<16),(34*3)|(35*3<<16),
    (35*3)|(36*3<<16),(36*3)|(37*3<<16),(38*3)|(39*3<<16),(39*3)|(40*3<<16),
    (40*3)|(41*3<<16),(42*3)|(43*3<<16),(43*3)|(44*3<<16),(44*3)|(45*3<<16),
    (46*3)|(47*3<<16),(47*3)|(48*3<<16),(48*3)|(49*3<<16)};

__global__ __launch_bounds__(BLOCK) void reg_loss_main(
        const float* __restrict__ preds, const float* __restrict__ targets,
        float* __restrict__ wsL, float* __restrict__ wsV) {
    __shared__ float pmS[TILE_ROWS][ROW + 1];   // masked preds, stride 152
    __shared__ float tmS[TILE_ROWS][ROW + 1];   // raw targets
    __shared__ float redL[4], redV[4];

    const int t = threadIdx.x;
    const int lane = t & 63;
    const int wave = t >> 6;

    float l1 = 0.f;
    float vel = 0.f;

    for (int tile = 0; tile < TILES_PER_BLOCK; ++tile) {
        const long long tileIdx = (long long)blockIdx.x * TILES_PER_BLOCK + tile;
        const float4* __restrict__ p4 =
            (const float4*)(preds + tileIdx * TILE_DWORDS);
        const float4* __restrict__ t4 =
            (const float4*)(targets + tileIdx * TILE_DWORDS);

        if (tile) __syncthreads();   // previous edge phase done before overwrite

        // ---- phase 1: coalesced float4 tile load + l1 + LDS stage ----
#pragma unroll
        for (int k = 0; k < 3; ++k) {
            int i = t + k * BLOCK;
            if (i < TILE_F4) {
                float4 pv = p4[i];
                float4 tv = t4[i];
                float pe[4] = {pv.x, pv.y, pv.z, pv.w};
                float te[4] = {tv.x, tv.y, tv.z, tv.w};
                int d0 = i * 4;
#pragma unroll
                for (int j = 0; j < 4; ++j) {
                    int d = d0 + j;
                    int r = d / ROW;            // magic-mul div
                    int c = d - r * ROW;
                    float tt = te[j];
                    float pm = (tt != 0.f) ? pe[j] : 0.f;
                    l1 += fabsf(pm - tt);
                    pmS[r][c] = pm;
                    tmS[r][c] = tt;
                }
            }
        }
        __syncthreads();

        // ---- phase 2: 752 edge tasks across all 256 threads ----
#pragma unroll
        for (int k = 0; k < 3; ++k) {
            int task = t + k * BLOCK;
            if (task < N_TASKS) {
                int r = task / N_EDGES;          // magic-mul div
                int e = task - r * N_EDGES;
                unsigned int pk = c_edge[e];
                int pi = pk & 0xffff;
                int ci = pk >> 16;
                float pdx = pmS[r][pi]     - pmS[r][ci];
                float pdy = pmS[r][pi + 1] - pmS[r][ci + 1];
                float pdz = pmS[r][pi + 2] - pmS[r][ci + 2];
                float tdx = tmS[r][pi]     - tmS[r][ci];
                float tdy = tmS[r][pi + 1] - tmS[r][ci + 1];
                float tdz = tmS[r][pi + 2] - tmS[r][ci + 2];
                const float eps = 1.17549435e-38f;  // fp32 tiny
                float pinv = 1.f / (sqrtf(pdx*pdx + pdy*pdy + pdz*pdz) + eps);
                float tinv = 1.f / (sqrtf(tdx*tdx + tdy*tdy + tdz*tdz) + eps);
                float dx = pdx * pinv - tdx * tinv;
                float dy = pdy * pinv - tdy * tinv;
                float dz = pdz * pinv - tdz * tinv;
                float m0 = (tmS[r][e]      != 0.f) ? 1.f : 0.f;
                float m1 = (tmS[r][47 + e] != 0.f) ? 1.f : 0.f;
                float m2 = (tmS[r][94 + e] != 0.f) ? 1.f : 0.f;
                vel += m0 * dx * dx + m1 * dy * dy + m2 * dz * dz;
            }
        }
    }

    // ---- block reduction -> per-block partials ----
#pragma unroll
    for (int off = 32; off > 0; off >>= 1) {
        l1  += __shfl_down(l1, off);
        vel += __shfl_down(vel, off);
    }
    if (lane == 0) { redL[wave] = l1; redV[wave] = vel; }
    __syncthreads();
    if (t == 0) {
        wsL[blockIdx.x] = redL[0] + redL[1] + redL[2] + redL[3];
        wsV[blockIdx.x] = redV[0] + redV[1] + redV[2] + redV[3];
    }
}

__global__ __launch_bounds__(BLOCK) void reg_loss_finalize(
        const float* __restrict__ wsL, const float* __restrict__ wsV,
        float* __restrict__ out) {
    __shared__ double rl[4], rv[4];
    const int t = threadIdx.x;
    const int lane = t & 63;
    const int wave = t >> 6;
    double L = 0.0, V = 0.0;
    for (int k = t; k < GRID; k += BLOCK) { L += wsL[k]; V += wsV[k]; }
#pragma unroll
    for (int off = 32; off > 0; off >>= 1) {
        L += __shfl_down(L, off);
        V += __shfl_down(V, off);
    }
    if (lane == 0) { rl[wave] = L; rv[wave] = V; }
    __syncthreads();
    if (t == 0) {
        double Ls = rl[0] + rl[1] + rl[2] + rl[3];
        double Vs = rv[0] + rv[1] + rv[2] + rv[3];
        out[0] = (float)(Ls / ((double)N_ROWS * 151.0)
                       + 0.1 * (Vs / ((double)N_ROWS * 141.0)));
    }
}

extern "C" void kernel_launch(void* const* d_in, const int* in_sizes, int n_in,
                              void* d_out, int out_size, void* d_ws, size_t ws_size,
                              hipStream_t stream) {
    const float* preds   = (const float*)d_in[0];
    const float* targets = (const float*)d_in[1];
    float* wsL = (float*)d_ws;
    float* wsV = wsL + GRID;
    float* out = (float*)d_out;

    reg_loss_main<<<GRID, BLOCK, 0, stream>>>(preds, targets, wsL, wsV);
    reg_loss_finalize<<<1, BLOCK, 0, stream>>>(wsL, wsV, out);
}

// Round 3
// 182.999 us; speedup vs baseline: 1.0898x; 1.0338x over previous
//
#include <hip/hip_runtime.h>

// RegLoss: l1(masked preds, targets) + 0.1 * mse(masked edge directions)
// preds, targets: [128, 1024, 151] fp32. Output: 1 fp32 scalar.
//
// Identities:
//   targets * (targets != 0) == targets       (masking targets is identity)
//   (m*pd - m*td)^2 == m*(pd - td)^2          (m in {0,1})
// directs channel c = comp*47 + edge; mask applied to it is mask[comp*47+edge]
// of the same row.
//
// Wave-autonomous structure (NO __syncthreads in hot path): each wave stages
// its own 4 rows into its private LDS slice (interleaved {pm, tm} pairs so
// phase-2 reads are ds_read_b64), then computes its own 188 edge tasks.
// Intra-wave LDS RAW is ordered by compiler lgkmcnt waits (wave64 lockstep).
// Phase-1 writes are ds_write_b128 at consecutive 16B per lane: conflict-free.

#define N_ROWS   (128 * 1024)
#define ROW      151
#define N_EDGES  47
#define GRID     8192
#define BLOCK    256
#define ROWS_PER_WAVE 4                     // GRID * 4 waves * 4 rows = N_ROWS
#define WAVE_DWORDS (ROWS_PER_WAVE * ROW)   // 604 (divisible by 4 -> 16B tiles)
#define WAVE_F4 (WAVE_DWORDS / 4)           // 151 float4 per array per wave
#define WAVE_TASKS (ROWS_PER_WAVE * N_EDGES) // 188
#define S_STRIDE (ROW * 2)                  // interleaved row stride (dwords)

// packed: low16 = parent*6 (interleaved dword offset), high16 = child*6
#define E(p, c) ((unsigned)((p) * 6) | ((unsigned)((c) * 6) << 16))
__constant__ unsigned c_edge[N_EDGES] = {
    E(0,1),  E(1,2),  E(2,3),  E(3,29), E(1,5),  E(5,6),  E(6,8),  E(8,9),
    E(8,13), E(8,17), E(8,21), E(8,25), E(9,10), E(10,11),E(11,12),E(13,14),
    E(14,15),E(15,16),E(17,18),E(18,19),E(19,20),E(21,22),E(22,23),E(23,24),
    E(25,26),E(26,27),E(27,28),E(29,30),E(29,34),E(29,38),E(29,42),E(29,46),
    E(30,31),E(31,32),E(32,33),E(34,35),E(35,36),E(36,37),E(38,39),E(39,40),
    E(40,41),E(42,43),E(43,44),E(44,45),E(46,47),E(47,48),E(48,49)};

__global__ __launch_bounds__(BLOCK) void reg_loss_main(
        const float* __restrict__ preds, const float* __restrict__ targets,
        float* __restrict__ wsL, float* __restrict__ wsV) {
    __shared__ float S[4][ROWS_PER_WAVE * S_STRIDE];   // per-wave slice, 4832 B
    __shared__ float redL[4], redV[4];

    const int t = threadIdx.x;
    const int lane = t & 63;
    const int wave = t >> 6;
    float* __restrict__ Sw = S[wave];
    float4* __restrict__ S4 = (float4*)Sw;

    const long long base = ((long long)blockIdx.x * 4 + wave) * WAVE_DWORDS;
    const float4* __restrict__ p4 = (const float4*)(preds + base);
    const float4* __restrict__ t4 = (const float4*)(targets + base);

    float l1 = 0.f;
    float vel = 0.f;

    // ---- phase 1: stage own 4 rows, interleaved {pm, tm}; compute l1 ----
#pragma unroll
    for (int k = 0; k < 3; ++k) {
        int i = lane + k * 64;
        if (i < WAVE_F4) {
            float4 pv = p4[i];
            float4 tv = t4[i];
            float4 pm;
            pm.x = (tv.x != 0.f) ? pv.x : 0.f;
            pm.y = (tv.y != 0.f) ? pv.y : 0.f;
            pm.z = (tv.z != 0.f) ? pv.z : 0.f;
            pm.w = (tv.w != 0.f) ? pv.w : 0.f;
            l1 += fabsf(pm.x - tv.x) + fabsf(pm.y - tv.y)
                + fabsf(pm.z - tv.z) + fabsf(pm.w - tv.w);
            float4 a = {pm.x, tv.x, pm.y, tv.y};
            float4 b = {pm.z, tv.z, pm.w, tv.w};
            S4[i * 2]     = a;     // ds_write_b128, lanes consecutive 32B
            S4[i * 2 + 1] = b;
        }
    }
    // no __syncthreads: wave reads only its own slice (lgkmcnt handles RAW)

    // ---- phase 2: 188 edge tasks over 64 lanes ----
#pragma unroll
    for (int k = 0; k < 3; ++k) {
        int task = lane + k * 64;
        if (task < WAVE_TASKS) {
            int r = task / N_EDGES;            // magic-mul
            int e = task - r * N_EDGES;
            const float* __restrict__ R = Sw + r * S_STRIDE;
            unsigned pk = c_edge[e];
            int pi = pk & 0xffff;              // parent*6 (even -> 8B aligned)
            int ci = pk >> 16;                 // child*6
            float2 px = *(const float2*)(R + pi);
            float2 py = *(const float2*)(R + pi + 2);
            float2 pz = *(const float2*)(R + pi + 4);
            float2 cx = *(const float2*)(R + ci);
            float2 cy = *(const float2*)(R + ci + 2);
            float2 cz = *(const float2*)(R + ci + 4);
            float pdx = px.x - cx.x, pdy = py.x - cy.x, pdz = pz.x - cz.x;
            float tdx = px.y - cx.y, tdy = py.y - cy.y, tdz = pz.y - cz.y;
            const float eps = 1.17549435e-38f;  // fp32 tiny
            float pinv = 1.f / (sqrtf(pdx*pdx + pdy*pdy + pdz*pdz) + eps);
            float tinv = 1.f / (sqrtf(tdx*tdx + tdy*tdy + tdz*tdz) + eps);
            float dx = pdx * pinv - tdx * tinv;
            float dy = pdy * pinv - tdy * tinv;
            float dz = pdz * pinv - tdz * tinv;
            float m0 = (R[e * 2 + 1]        != 0.f) ? 1.f : 0.f;
            float m1 = (R[(47 + e) * 2 + 1] != 0.f) ? 1.f : 0.f;
            float m2 = (R[(94 + e) * 2 + 1] != 0.f) ? 1.f : 0.f;
            vel += m0 * dx * dx + m1 * dy * dy + m2 * dz * dz;
        }
    }

    // ---- block reduction -> per-block partials ----
#pragma unroll
    for (int off = 32; off > 0; off >>= 1) {
        l1  += __shfl_down(l1, off);
        vel += __shfl_down(vel, off);
    }
    if (lane == 0) { redL[wave] = l1; redV[wave] = vel; }
    __syncthreads();
    if (t == 0) {
        wsL[blockIdx.x] = redL[0] + redL[1] + redL[2] + redL[3];
        wsV[blockIdx.x] = redV[0] + redV[1] + redV[2] + redV[3];
    }
}

__global__ __launch_bounds__(BLOCK) void reg_loss_finalize(
        const float* __restrict__ wsL, const float* __restrict__ wsV,
        float* __restrict__ out) {
    __shared__ double rl[4], rv[4];
    const int t = threadIdx.x;
    const int lane = t & 63;
    const int wave = t >> 6;
    double L = 0.0, V = 0.0;
    for (int k = t; k < GRID; k += BLOCK) { L += wsL[k]; V += wsV[k]; }
#pragma unroll
    for (int off = 32; off > 0; off >>= 1) {
        L += __shfl_down(L, off);
        V += __shfl_down(V, off);
    }
    if (lane == 0) { rl[wave] = L; rv[wave] = V; }
    __syncthreads();
    if (t == 0) {
        double Ls = rl[0] + rl[1] + rl[2] + rl[3];
        double Vs = rv[0] + rv[1] + rv[2] + rv[3];
        out[0] = (float)(Ls / ((double)N_ROWS * 151.0)
                       + 0.1 * (Vs / ((double)N_ROWS * 141.0)));
    }
}

extern "C" void kernel_launch(void* const* d_in, const int* in_sizes, int n_in,
                              void* d_out, int out_size, void* d_ws, size_t ws_size,
                              hipStream_t stream) {
    const float* preds   = (const float*)d_in[0];
    const float* targets = (const float*)d_in[1];
    float* wsL = (float*)d_ws;
    float* wsV = wsL + GRID;
    float* out = (float*)d_out;

    reg_loss_main<<<GRID, BLOCK, 0, stream>>>(preds, targets, wsL, wsV);
    reg_loss_finalize<<<1, BLOCK, 0, stream>>>(wsL, wsV, out);
}

// Round 4
// 180.730 us; speedup vs baseline: 1.1035x; 1.0126x over previous
//
#include <hip/hip_runtime.h>

// RegLoss: l1(masked preds, targets) + 0.1 * mse(masked edge directions)
// preds, targets: [128, 1024, 151] fp32. Output: 1 fp32 scalar.
//
// Identities:
//   targets * (targets != 0) == targets       (masking targets is identity)
//   (m*pd - m*td)^2 == m*(pd - td)^2          (m in {0,1})
//   diff/(len+tiny) == (d2 > 0 ? diff*rsq(d2) : 0) to ~1e-7 rel (threshold 2.4e-2)
//
// Wave-autonomous structure (NO __syncthreads in hot path): each wave stages
// its own 4 rows into its private LDS slice (interleaved {pm, tm} pairs so
// phase-2 reads are ds_read_b64), then computes its own 188 edge tasks.
// Phase 2 uses v_rsq_f32 instead of precise sqrt + precise divide (those
// expand to ~20 VALU instr each without fast-math — R3 showed VALUBusy 35%
// dominated by exactly that).

#define N_ROWS   (128 * 1024)
#define ROW      151
#define N_EDGES  47
#define GRID     8192
#define BLOCK    256
#define ROWS_PER_WAVE 4                     // GRID * 4 waves * 4 rows = N_ROWS
#define WAVE_DWORDS (ROWS_PER_WAVE * ROW)   // 604 (divisible by 4 -> 16B tiles)
#define WAVE_F4 (WAVE_DWORDS / 4)           // 151 float4 per array per wave
#define WAVE_TASKS (ROWS_PER_WAVE * N_EDGES) // 188
#define S_STRIDE (ROW * 2)                  // interleaved row stride (dwords)

#if __has_builtin(__builtin_amdgcn_rsqf)
__device__ __forceinline__ float fast_rsq(float x) { return __builtin_amdgcn_rsqf(x); }
#else
__device__ __forceinline__ float fast_rsq(float x) {
    float r; asm volatile("v_rsq_f32 %0, %1" : "=v"(r) : "v"(x)); return r;
}
#endif

// packed: low16 = parent*6 (interleaved dword offset), high16 = child*6
#define E(p, c) ((unsigned)((p) * 6) | ((unsigned)((c) * 6) << 16))
__constant__ unsigned c_edge[N_EDGES] = {
    E(0,1),  E(1,2),  E(2,3),  E(3,29), E(1,5),  E(5,6),  E(6,8),  E(8,9),
    E(8,13), E(8,17), E(8,21), E(8,25), E(9,10), E(10,11),E(11,12),E(13,14),
    E(14,15),E(15,16),E(17,18),E(18,19),E(19,20),E(21,22),E(22,23),E(23,24),
    E(25,26),E(26,27),E(27,28),E(29,30),E(29,34),E(29,38),E(29,42),E(29,46),
    E(30,31),E(31,32),E(32,33),E(34,35),E(35,36),E(36,37),E(38,39),E(39,40),
    E(40,41),E(42,43),E(43,44),E(44,45),E(46,47),E(47,48),E(48,49)};

__global__ __launch_bounds__(BLOCK) void reg_loss_main(
        const float* __restrict__ preds, const float* __restrict__ targets,
        float* __restrict__ wsL, float* __restrict__ wsV) {
    __shared__ float S[4][ROWS_PER_WAVE * S_STRIDE];   // per-wave slice, 4832 B
    __shared__ float redL[4], redV[4];

    const int t = threadIdx.x;
    const int lane = t & 63;
    const int wave = t >> 6;
    float* __restrict__ Sw = S[wave];
    float4* __restrict__ S4 = (float4*)Sw;

    const long long base = ((long long)blockIdx.x * 4 + wave) * WAVE_DWORDS;
    const float4* __restrict__ p4 = (const float4*)(preds + base);
    const float4* __restrict__ t4 = (const float4*)(targets + base);

    // ---- precompute phase-2 task descriptors (overlaps global latency) ----
    int tr[3], te[3], tpi[3], tci[3];
#pragma unroll
    for (int k = 0; k < 3; ++k) {
        int task = lane + k * 64;
        int r = task / N_EDGES;            // magic-mul
        int e = task - r * N_EDGES;
        if (task >= WAVE_TASKS) { r = 0; e = 0; }   // inert clamp
        tr[k] = r; te[k] = e;
        unsigned pk = c_edge[e];
        tpi[k] = pk & 0xffff;
        tci[k] = pk >> 16;
    }

    float l1 = 0.f;
    float vel = 0.f;

    // ---- phase 1: stage own 4 rows, interleaved {pm, tm}; compute l1 ----
#pragma unroll
    for (int k = 0; k < 3; ++k) {
        int i = lane + k * 64;
        if (i < WAVE_F4) {
            float4 pv = p4[i];
            float4 tv = t4[i];
            float4 pm;
            pm.x = (tv.x != 0.f) ? pv.x : 0.f;
            pm.y = (tv.y != 0.f) ? pv.y : 0.f;
            pm.z = (tv.z != 0.f) ? pv.z : 0.f;
            pm.w = (tv.w != 0.f) ? pv.w : 0.f;
            l1 += fabsf(pm.x - tv.x) + fabsf(pm.y - tv.y)
                + fabsf(pm.z - tv.z) + fabsf(pm.w - tv.w);
            float4 a = {pm.x, tv.x, pm.y, tv.y};
            float4 b = {pm.z, tv.z, pm.w, tv.w};
            S4[i * 2]     = a;     // ds_write_b128, lanes consecutive 32B
            S4[i * 2 + 1] = b;
        }
    }
    // no __syncthreads: wave reads only its own slice (lgkmcnt handles RAW)

    // ---- phase 2: 188 edge tasks over 64 lanes ----
#pragma unroll
    for (int k = 0; k < 3; ++k) {
        int task = lane + k * 64;
        if (task < WAVE_TASKS) {
            const float* __restrict__ R = Sw + tr[k] * S_STRIDE;
            int pi = tpi[k], ci = tci[k], e = te[k];
            float2 px = *(const float2*)(R + pi);
            float2 py = *(const float2*)(R + pi + 2);
            float2 pz = *(const float2*)(R + pi + 4);
            float2 cx = *(const float2*)(R + ci);
            float2 cy = *(const float2*)(R + ci + 2);
            float2 cz = *(const float2*)(R + ci + 4);
            float pdx = px.x - cx.x, pdy = py.x - cy.x, pdz = pz.x - cz.x;
            float tdx = px.y - cx.y, tdy = py.y - cy.y, tdz = pz.y - cz.y;
            float pd2 = pdx * pdx + pdy * pdy + pdz * pdz;
            float td2 = tdx * tdx + tdy * tdy + tdz * tdz;
            float pinv = (pd2 > 0.f) ? fast_rsq(pd2) : 0.f;
            float tinv = (td2 > 0.f) ? fast_rsq(td2) : 0.f;
            float dx = pdx * pinv - tdx * tinv;
            float dy = pdy * pinv - tdy * tinv;
            float dz = pdz * pinv - tdz * tinv;
            float m0 = (R[e * 2 + 1]        != 0.f) ? 1.f : 0.f;
            float m1 = (R[(47 + e) * 2 + 1] != 0.f) ? 1.f : 0.f;
            float m2 = (R[(94 + e) * 2 + 1] != 0.f) ? 1.f : 0.f;
            vel += m0 * dx * dx + m1 * dy * dy + m2 * dz * dz;
        }
    }

    // ---- block reduction -> per-block partials ----
#pragma unroll
    for (int off = 32; off > 0; off >>= 1) {
        l1  += __shfl_down(l1, off);
        vel += __shfl_down(vel, off);
    }
    if (lane == 0) { redL[wave] = l1; redV[wave] = vel; }
    __syncthreads();
    if (t == 0) {
        wsL[blockIdx.x] = redL[0] + redL[1] + redL[2] + redL[3];
        wsV[blockIdx.x] = redV[0] + redV[1] + redV[2] + redV[3];
    }
}

__global__ __launch_bounds__(BLOCK) void reg_loss_finalize(
        const float* __restrict__ wsL, const float* __restrict__ wsV,
        float* __restrict__ out) {
    __shared__ double rl[4], rv[4];
    const int t = threadIdx.x;
    const int lane = t & 63;
    const int wave = t >> 6;
    double L = 0.0, V = 0.0;
    for (int k = t; k < GRID; k += BLOCK) { L += wsL[k]; V += wsV[k]; }
#pragma unroll
    for (int off = 32; off > 0; off >>= 1) {
        L += __shfl_down(L, off);
        V += __shfl_down(V, off);
    }
    if (lane == 0) { rl[wave] = L; rv[wave] = V; }
    __syncthreads();
    if (t == 0) {
        double Ls = rl[0] + rl[1] + rl[2] + rl[3];
        double Vs = rv[0] + rv[1] + rv[2] + rv[3];
        out[0] = (float)(Ls / ((double)N_ROWS * 151.0)
                       + 0.1 * (Vs / ((double)N_ROWS * 141.0)));
    }
}

extern "C" void kernel_launch(void* const* d_in, const int* in_sizes, int n_in,
                              void* d_out, int out_size, void* d_ws, size_t ws_size,
                              hipStream_t stream) {
    const float* preds   = (const float*)d_in[0];
    const float* targets = (const float*)d_in[1];
    float* wsL = (float*)d_ws;
    float* wsV = wsL + GRID;
    float* out = (float*)d_out;

    reg_loss_main<<<GRID, BLOCK, 0, stream>>>(preds, targets, wsL, wsV);
    reg_loss_finalize<<<1, BLOCK, 0, stream>>>(wsL, wsV, out);
}

// Round 5
// 179.802 us; speedup vs baseline: 1.1092x; 1.0052x over previous
//
#include <hip/hip_runtime.h>

// RegLoss: l1(masked preds, targets) + 0.1 * mse(masked edge directions)
// preds, targets: [128, 1024, 151] fp32. Output: 1 fp32 scalar.
//
// Identities:
//   targets * (targets != 0) == targets       (masking targets is identity)
//   (m*pd - m*td)^2 == m*(pd - td)^2          (m in {0,1})
//   diff/(len+tiny) == (d2 > 0 ? diff*rsq(d2) : 0)  (~1e-7 rel; thresh 2.4e-2)
//
// R5: persistent-wave pipeline. 1024 blocks co-resident (4 blocks/CU at
// ~16 waves/CU). Each wave owns 8 contiguous chunks of 4 rows. Register
// prefetch: chunk c+1's 6 float4 loads issue before chunk c's compute, so
// global latency hides behind compute instead of being exposed per wave
// (R4 showed 100K/149K cycles per CU unaccounted = latency/dispatch floor
// from 32768 one-shot waves / 8192 WGs).
// Wave-private LDS slice reused per chunk; DS pipe is in-order per wave ->
// no __syncthreads in the hot path.

#define N_ROWS   (128 * 1024)
#define ROW      151
#define N_EDGES  47
#define GRID     1024
#define BLOCK    256
#define WAVE_CHUNKS 8                  // 1024 blk * 4 waves * 8 chunks * 4 rows
#define CHUNK_ROWS 4
#define CHUNK_DWORDS (CHUNK_ROWS * ROW)  // 604
#define CHUNK_F4 (CHUNK_DWORDS / 4)      // 151 float4 per array per chunk
#define CHUNK_TASKS (CHUNK_ROWS * N_EDGES) // 188
#define S_STRIDE (ROW * 2)               // interleaved {pm,tm} row stride

#if __has_builtin(__builtin_amdgcn_rsqf)
__device__ __forceinline__ float fast_rsq(float x) { return __builtin_amdgcn_rsqf(x); }
#else
__device__ __forceinline__ float fast_rsq(float x) {
    float r; asm volatile("v_rsq_f32 %0, %1" : "=v"(r) : "v"(x)); return r;
}
#endif

// packed: low16 = parent*6 (interleaved dword offset), high16 = child*6
#define E(p, c) ((unsigned)((p) * 6) | ((unsigned)((c) * 6) << 16))
__constant__ unsigned c_edge[N_EDGES] = {
    E(0,1),  E(1,2),  E(2,3),  E(3,29), E(1,5),  E(5,6),  E(6,8),  E(8,9),
    E(8,13), E(8,17), E(8,21), E(8,25), E(9,10), E(10,11),E(11,12),E(13,14),
    E(14,15),E(15,16),E(17,18),E(18,19),E(19,20),E(21,22),E(22,23),E(23,24),
    E(25,26),E(26,27),E(27,28),E(29,30),E(29,34),E(29,38),E(29,42),E(29,46),
    E(30,31),E(31,32),E(32,33),E(34,35),E(35,36),E(36,37),E(38,39),E(39,40),
    E(40,41),E(42,43),E(43,44),E(44,45),E(46,47),E(47,48),E(48,49)};

__global__ __launch_bounds__(BLOCK) void reg_loss_main(
        const float* __restrict__ preds, const float* __restrict__ targets,
        float* __restrict__ wsL, float* __restrict__ wsV) {
    __shared__ float S[4][CHUNK_ROWS * S_STRIDE];   // per-wave slice, 4832 B
    __shared__ float redL[4], redV[4];

    const int t = threadIdx.x;
    const int lane = t & 63;
    const int wave = t >> 6;
    float* __restrict__ Sw = S[wave];
    float4* __restrict__ S4 = (float4*)Sw;

    const long long wbase =
        ((long long)blockIdx.x * 4 + wave) * (WAVE_CHUNKS * CHUNK_DWORDS);
    const float4* __restrict__ p4 = (const float4*)(preds + wbase);
    const float4* __restrict__ t4 = (const float4*)(targets + wbase);

    // ---- per-lane phase-2 task descriptors (fixed across chunks) ----
    int tRoff[3], tpi[3], tci[3], tm0[3];
    bool tact[3];
#pragma unroll
    for (int k = 0; k < 3; ++k) {
        int task = lane + k * 64;
        tact[k] = task < CHUNK_TASKS;
        int r = task / N_EDGES;              // magic-mul
        int e = task - r * N_EDGES;
        if (!tact[k]) { r = 0; e = 0; }
        tRoff[k] = r * S_STRIDE;
        unsigned pk = c_edge[e];
        tpi[k] = pk & 0xffff;
        tci[k] = pk >> 16;
        tm0[k] = e * 2 + 1;                  // tm of mask channel comp0
    }

    float l1 = 0.f;
    float vel = 0.f;

    // ---- prefetch chunk 0 into registers ----
    float4 Pp[3], Pt[3];
#pragma unroll
    for (int k = 0; k < 3; ++k) {
        int i = lane + k * 64;
        if (i < CHUNK_F4) { Pp[k] = p4[i]; Pt[k] = t4[i]; }
    }

#pragma unroll
    for (int c = 0; c < WAVE_CHUNKS; ++c) {
        // consume current prefetch
        float4 Cp[3], Ct[3];
#pragma unroll
        for (int k = 0; k < 3; ++k) { Cp[k] = Pp[k]; Ct[k] = Pt[k]; }

        // issue next chunk's loads (overlap with compute below)
        if (c + 1 < WAVE_CHUNKS) {
            const float4* np4 = p4 + (long long)(c + 1) * CHUNK_F4;
            const float4* nt4 = t4 + (long long)(c + 1) * CHUNK_F4;
#pragma unroll
            for (int k = 0; k < 3; ++k) {
                int i = lane + k * 64;
                if (i < CHUNK_F4) { Pp[k] = np4[i]; Pt[k] = nt4[i]; }
            }
        }

        // ---- mask + l1 + LDS stage (interleaved {pm,tm}) ----
#pragma unroll
        for (int k = 0; k < 3; ++k) {
            int i = lane + k * 64;
            if (i < CHUNK_F4) {
                float4 pv = Cp[k], tv = Ct[k];
                float4 pm;
                pm.x = (tv.x != 0.f) ? pv.x : 0.f;
                pm.y = (tv.y != 0.f) ? pv.y : 0.f;
                pm.z = (tv.z != 0.f) ? pv.z : 0.f;
                pm.w = (tv.w != 0.f) ? pv.w : 0.f;
                l1 += fabsf(pm.x - tv.x) + fabsf(pm.y - tv.y)
                    + fabsf(pm.z - tv.z) + fabsf(pm.w - tv.w);
                float4 a = {pm.x, tv.x, pm.y, tv.y};
                float4 b = {pm.z, tv.z, pm.w, tv.w};
                S4[i * 2]     = a;    // ds_write_b128, consecutive 32B/lane
                S4[i * 2 + 1] = b;
            }
        }

        // ---- 188 edge tasks over 64 lanes (wave-private LDS, no barrier) ----
#pragma unroll
        for (int k = 0; k < 3; ++k) {
            if (tact[k]) {
                const float* __restrict__ R = Sw + tRoff[k];
                int pi = tpi[k], ci = tci[k], me = tm0[k];
                float2 px = *(const float2*)(R + pi);
                float2 py = *(const float2*)(R + pi + 2);
                float2 pz = *(const float2*)(R + pi + 4);
                float2 cx = *(const float2*)(R + ci);
                float2 cy = *(const float2*)(R + ci + 2);
                float2 cz = *(const float2*)(R + ci + 4);
                float pdx = px.x - cx.x, pdy = py.x - cy.x, pdz = pz.x - cz.x;
                float tdx = px.y - cx.y, tdy = py.y - cy.y, tdz = pz.y - cz.y;
                float pd2 = pdx * pdx + pdy * pdy + pdz * pdz;
                float td2 = tdx * tdx + tdy * tdy + tdz * tdz;
                float pinv = (pd2 > 0.f) ? fast_rsq(pd2) : 0.f;
                float tinv = (td2 > 0.f) ? fast_rsq(td2) : 0.f;
                float dx = pdx * pinv - tdx * tinv;
                float dy = pdy * pinv - tdy * tinv;
                float dz = pdz * pinv - tdz * tinv;
                float m0 = (R[me]       != 0.f) ? 1.f : 0.f;
                float m1 = (R[me + 94]  != 0.f) ? 1.f : 0.f;
                float m2 = (R[me + 188] != 0.f) ? 1.f : 0.f;
                vel += m0 * dx * dx + m1 * dy * dy + m2 * dz * dz;
            }
        }
    }

    // ---- block reduction -> per-block partials ----
#pragma unroll
    for (int off = 32; off > 0; off >>= 1) {
        l1  += __shfl_down(l1, off);
        vel += __shfl_down(vel, off);
    }
    if (lane == 0) { redL[wave] = l1; redV[wave] = vel; }
    __syncthreads();
    if (t == 0) {
        wsL[blockIdx.x] = redL[0] + redL[1] + redL[2] + redL[3];
        wsV[blockIdx.x] = redV[0] + redV[1] + redV[2] + redV[3];
    }
}

__global__ __launch_bounds__(BLOCK) void reg_loss_finalize(
        const float* __restrict__ wsL, const float* __restrict__ wsV,
        float* __restrict__ out) {
    __shared__ double rl[4], rv[4];
    const int t = threadIdx.x;
    const int lane = t & 63;
    const int wave = t >> 6;
    double L = 0.0, V = 0.0;
    for (int k = t; k < GRID; k += BLOCK) { L += wsL[k]; V += wsV[k]; }
#pragma unroll
    for (int off = 32; off > 0; off >>= 1) {
        L += __shfl_down(L, off);
        V += __shfl_down(V, off);
    }
    if (lane == 0) { rl[wave] = L; rv[wave] = V; }
    __syncthreads();
    if (t == 0) {
        double Ls = rl[0] + rl[1] + rl[2] + rl[3];
        double Vs = rv[0] + rv[1] + rv[2] + rv[3];
        out[0] = (float)(Ls / ((double)N_ROWS * 151.0)
                       + 0.1 * (Vs / ((double)N_ROWS * 141.0)));
    }
}

extern "C" void kernel_launch(void* const* d_in, const int* in_sizes, int n_in,
                              void* d_out, int out_size, void* d_ws, size_t ws_size,
                              hipStream_t stream) {
    const float* preds   = (const float*)d_in[0];
    const float* targets = (const float*)d_in[1];
    float* wsL = (float*)d_ws;
    float* wsV = wsL + GRID;
    float* out = (float*)d_out;

    reg_loss_main<<<GRID, BLOCK, 0, stream>>>(preds, targets, wsL, wsV);
    reg_loss_finalize<<<1, BLOCK, 0, stream>>>(wsL, wsV, out);
}

// Round 6
// 178.687 us; speedup vs baseline: 1.1161x; 1.0062x over previous
//
#include <hip/hip_runtime.h>

// RegLoss: l1(masked preds, targets) + 0.1 * mse(masked edge directions)
// preds, targets: [128, 1024, 151] fp32. Output: 1 fp32 scalar.
//
// Identities:
//   targets * (targets != 0) == targets       (masking targets is identity)
//   (m*pd - m*td)^2 == m*(pd - td)^2          (m in {0,1})
//   diff/(len+tiny) == (d2 > 0 ? diff*rsq(d2) : 0)  (~1e-7 rel; thresh 2.4e-2)
//
// R6: VGPR-free async pipeline via __builtin_amdgcn_global_load_lds (16B).
// R5's register prefetch was defeated by the allocator (VGPR=48 < needed)
// -> every chunk serially exposed global latency. DMA staging costs zero
// VGPRs, so a depth-2 LDS double-buffer pipeline survives codegen:
//   prologue: DMA(c0->B0), DMA(c1->B1)
//   loop c:   s_waitcnt vmcnt(6)   // all of DMA(c) done, DMA(c+1) in flight
//             compute(B[c&1]); s_waitcnt lgkmcnt(0); DMA(c+2 -> B[c&1])
// Raw (non-interleaved) layout because DMA scatter is lane-ordered; the
// pm mask is applied at read time (VALU is ~84% idle, cndmask is free).

#define N_ROWS   (128 * 1024)
#define ROW      151
#define N_EDGES  47
#define GRID     2048
#define BLOCK    256
#define CHUNKS   4                     // 2048 blk * 4 waves * 4 chunks * 4 rows
#define CHUNK_ROWS 4
#define CHUNK_DW (CHUNK_ROWS * ROW)    // 604 dwords per array per chunk
#define CHUNK_TASKS (CHUNK_ROWS * N_EDGES) // 188
#define BUF_DW (2 * CHUNK_DW)          // [preds 604][targets 604]

#if __has_builtin(__builtin_amdgcn_rsqf)
__device__ __forceinline__ float fast_rsq(float x) { return __builtin_amdgcn_rsqf(x); }
#else
__device__ __forceinline__ float fast_rsq(float x) {
    float r; asm volatile("v_rsq_f32 %0, %1" : "=v"(r) : "v"(x)); return r;
}
#endif

template <int N>
__device__ __forceinline__ void wait_vm() {
    asm volatile("s_waitcnt vmcnt(%0)" :: "n"(N) : "memory");
}
__device__ __forceinline__ void wait_lgkm0() {
    asm volatile("s_waitcnt lgkmcnt(0)" ::: "memory");
}

__device__ __forceinline__ void dma16(const float* g, float* l) {
    __builtin_amdgcn_global_load_lds(
        (const __attribute__((address_space(1))) unsigned*)g,
        (__attribute__((address_space(3))) unsigned*)l, 16, 0, 0);
}

// 6 DMA instructions per chunk: 2x1024B + 368B tail per array.
__device__ __forceinline__ void dma_chunk(const float* gp, const float* gt,
                                          float* L, int lane) {
    const int l4 = lane * 4;
    dma16(gp + l4,        L);
    dma16(gp + 256 + l4,  L + 256);
    dma16(gt + l4,        L + CHUNK_DW);
    dma16(gt + 256 + l4,  L + CHUNK_DW + 256);
    if (lane < 23) {                       // 23*16B = 368B tail (604-512 dw)
        dma16(gp + 512 + l4, L + 512);
        dma16(gt + 512 + l4, L + CHUNK_DW + 512);
    }
}

// packed: low16 = parent*3 (dword offset in row), high16 = child*3
#define E(p, c) ((unsigned)((p) * 3) | ((unsigned)((c) * 3) << 16))
__constant__ unsigned c_edge[N_EDGES] = {
    E(0,1),  E(1,2),  E(2,3),  E(3,29), E(1,5),  E(5,6),  E(6,8),  E(8,9),
    E(8,13), E(8,17), E(8,21), E(8,25), E(9,10), E(10,11),E(11,12),E(13,14),
    E(14,15),E(15,16),E(17,18),E(18,19),E(19,20),E(21,22),E(22,23),E(23,24),
    E(25,26),E(26,27),E(27,28),E(29,30),E(29,34),E(29,38),E(29,42),E(29,46),
    E(30,31),E(31,32),E(32,33),E(34,35),E(35,36),E(36,37),E(38,39),E(39,40),
    E(40,41),E(42,43),E(43,44),E(44,45),E(46,47),E(47,48),E(48,49)};

struct TaskDesc { int act[3], roff[3], pi[3], ci[3], me[3]; };

__device__ __forceinline__ void compute_chunk(
        const float* __restrict__ B, int lane, const TaskDesc& td,
        float& l1, float& vel) {
    const float* __restrict__ Bp = B;
    const float* __restrict__ Bt = B + CHUNK_DW;

    // ---- l1 over the chunk: lane-contiguous b128 LDS reads ----
#pragma unroll
    for (int k = 0; k < 3; ++k) {
        int i = lane + k * 64;
        if (i < CHUNK_DW / 4) {
            float4 pv = ((const float4*)Bp)[i];
            float4 tv = ((const float4*)Bt)[i];
            float a0 = (tv.x != 0.f) ? pv.x : 0.f;
            float a1 = (tv.y != 0.f) ? pv.y : 0.f;
            float a2 = (tv.z != 0.f) ? pv.z : 0.f;
            float a3 = (tv.w != 0.f) ? pv.w : 0.f;
            l1 += fabsf(a0 - tv.x) + fabsf(a1 - tv.y)
                + fabsf(a2 - tv.z) + fabsf(a3 - tv.w);
        }
    }

    // ---- 188 edge tasks, mask applied at read time ----
#pragma unroll
    for (int k = 0; k < 3; ++k) {
        if (td.act[k]) {
            const float* __restrict__ Rp = Bp + td.roff[k];
            const float* __restrict__ Rt = Bt + td.roff[k];
            int pi = td.pi[k], ci = td.ci[k], me = td.me[k];
            float tpx = Rt[pi], tpy = Rt[pi + 1], tpz = Rt[pi + 2];
            float tcx = Rt[ci], tcy = Rt[ci + 1], tcz = Rt[ci + 2];
            float ppx = Rp[pi], ppy = Rp[pi + 1], ppz = Rp[pi + 2];
            float pcx = Rp[ci], pcy = Rp[ci + 1], pcz = Rp[ci + 2];
            // masked preds
            float apx = (tpx != 0.f) ? ppx : 0.f;
            float apy = (tpy != 0.f) ? ppy : 0.f;
            float apz = (tpz != 0.f) ? ppz : 0.f;
            float acx = (tcx != 0.f) ? pcx : 0.f;
            float acy = (tcy != 0.f) ? pcy : 0.f;
            float acz = (tcz != 0.f) ? pcz : 0.f;
            float pdx = apx - acx, pdy = apy - acy, pdz = apz - acz;
            float tdx = tpx - tcx, tdy = tpy - tcy, tdz = tpz - tcz;
            float pd2 = pdx * pdx + pdy * pdy + pdz * pdz;
            float td2 = tdx * tdx + tdy * tdy + tdz * tdz;
            float pinv = (pd2 > 0.f) ? fast_rsq(pd2) : 0.f;
            float tinv = (td2 > 0.f) ? fast_rsq(td2) : 0.f;
            float dx = pdx * pinv - tdx * tinv;
            float dy = pdy * pinv - tdy * tinv;
            float dz = pdz * pinv - tdz * tinv;
            float m0 = (Rt[me]      != 0.f) ? 1.f : 0.f;
            float m1 = (Rt[me + 47] != 0.f) ? 1.f : 0.f;
            float m2 = (Rt[me + 94] != 0.f) ? 1.f : 0.f;
            vel += m0 * dx * dx + m1 * dy * dy + m2 * dz * dz;
        }
    }
}

__global__ __launch_bounds__(BLOCK) void reg_loss_main(
        const float* __restrict__ preds, const float* __restrict__ targets,
        float* __restrict__ wsL, float* __restrict__ wsV) {
    __shared__ float S[4][2][BUF_DW];      // 4 waves x 2 bufs x 4832B = 38.7 KB
    __shared__ float redL[4], redV[4];

    const int t = threadIdx.x;
    const int lane = t & 63;
    const int wave = t >> 6;
    float* B0 = &S[wave][0][0];
    float* B1 = &S[wave][1][0];

    const long long wb =
        (long long)(blockIdx.x * 4 + wave) * (CHUNKS * CHUNK_DW);
    const float* gp = preds + wb;
    const float* gt = targets + wb;

    // per-lane edge-task descriptors (fixed across chunks)
    TaskDesc td;
#pragma unroll
    for (int k = 0; k < 3; ++k) {
        int task = lane + k * 64;
        td.act[k] = task < CHUNK_TASKS;
        int r = task / N_EDGES;
        int e = task - r * N_EDGES;
        if (!td.act[k]) { r = 0; e = 0; }
        td.roff[k] = r * ROW;
        unsigned pk = c_edge[e];
        td.pi[k] = pk & 0xffff;
        td.ci[k] = pk >> 16;
        td.me[k] = e;
    }

    // ---- depth-2 DMA pipeline ----
    dma_chunk(gp,                gt,                B0, lane);   // chunk 0
    dma_chunk(gp + CHUNK_DW,     gt + CHUNK_DW,     B1, lane);   // chunk 1

    float l1 = 0.f, vel = 0.f;

    wait_vm<6>();                          // chunk 0 landed (chunk 1 in flight)
    compute_chunk(B0, lane, td, l1, vel);
    wait_lgkm0();                          // B0 reads retired before overwrite
    dma_chunk(gp + 2 * CHUNK_DW, gt + 2 * CHUNK_DW, B0, lane);   // chunk 2

    wait_vm<6>();                          // chunk 1 landed
    compute_chunk(B1, lane, td, l1, vel);
    wait_lgkm0();
    dma_chunk(gp + 3 * CHUNK_DW, gt + 3 * CHUNK_DW, B1, lane);   // chunk 3

    wait_vm<6>();                          // chunk 2 landed (only chunk 3 left)
    compute_chunk(B0, lane, td, l1, vel);

    wait_vm<0>();                          // chunk 3 landed
    compute_chunk(B1, lane, td, l1, vel);

    // ---- block reduction -> per-block partials ----
#pragma unroll
    for (int off = 32; off > 0; off >>= 1) {
        l1  += __shfl_down(l1, off);
        vel += __shfl_down(vel, off);
    }
    if (lane == 0) { redL[wave] = l1; redV[wave] = vel; }
    __syncthreads();
    if (t == 0) {
        wsL[blockIdx.x] = redL[0] + redL[1] + redL[2] + redL[3];
        wsV[blockIdx.x] = redV[0] + redV[1] + redV[2] + redV[3];
    }
}

__global__ __launch_bounds__(BLOCK) void reg_loss_finalize(
        const float* __restrict__ wsL, const float* __restrict__ wsV,
        float* __restrict__ out) {
    __shared__ double rl[4], rv[4];
    const int t = threadIdx.x;
    const int lane = t & 63;
    const int wave = t >> 6;
    double L = 0.0, V = 0.0;
    for (int k = t; k < GRID; k += BLOCK) { L += wsL[k]; V += wsV[k]; }
#pragma unroll
    for (int off = 32; off > 0; off >>= 1) {
        L += __shfl_down(L, off);
        V += __shfl_down(V, off);
    }
    if (lane == 0) { rl[wave] = L; rv[wave] = V; }
    __syncthreads();
    if (t == 0) {
        double Ls = rl[0] + rl[1] + rl[2] + rl[3];
        double Vs = rv[0] + rv[1] + rv[2] + rv[3];
        out[0] = (float)(Ls / ((double)N_ROWS * 151.0)
                       + 0.1 * (Vs / ((double)N_ROWS * 141.0)));
    }
}

extern "C" void kernel_launch(void* const* d_in, const int* in_sizes, int n_in,
                              void* d_out, int out_size, void* d_ws, size_t ws_size,
                              hipStream_t stream) {
    const float* preds   = (const float*)d_in[0];
    const float* targets = (const float*)d_in[1];
    float* wsL = (float*)d_ws;
    float* wsV = wsL + GRID;
    float* out = (float*)d_out;

    reg_loss_main<<<GRID, BLOCK, 0, stream>>>(preds, targets, wsL, wsV);
    reg_loss_finalize<<<1, BLOCK, 0, stream>>>(wsL, wsV, out);
}